// Round 1
// baseline (253.202 us; speedup 1.0000x reference)
//
#include <hip/hip_runtime.h>
#include <hip/hip_bf16.h>
#include <cstdint>
#include <cstddef>

#define B_ 4
#define N_ 4096
#define D_ 1024
#define K_ 256
#define M_ (B_ * N_)          // 16384 rows
#define P_ (6 * K_)           // 1536 proj cols
#define DK2_ (2 * K_)         // 512 rho cols

static __device__ __forceinline__ float sigm(float x) {
    return 1.0f / (1.0f + expf(-x));
}
static __device__ __forceinline__ float softplusf_(float x) {
    return fmaxf(x, 0.0f) + log1pf(expf(-fabsf(x)));
}
static __device__ __forceinline__ unsigned short f2bf(float f) {
    uint32_t u = __float_as_uint(f);
    uint32_t r = (u + 0x7FFFu + ((u >> 16) & 1u)) >> 16;
    return (unsigned short)r;
}

#define GATE_BIAS 0.6190392084062235f
#define AMP_MAX 3.0f

typedef __attribute__((ext_vector_type(8))) __bf16 bf16x8;
typedef __attribute__((ext_vector_type(4))) float f32x4;

// ---------------- fp32 -> bf16 convert ----------------
__global__ __launch_bounds__(256) void cvt_kernel(const float* __restrict__ src,
                                                  unsigned short* __restrict__ dst, int n4) {
    int i = blockIdx.x * 256 + threadIdx.x;
    if (i < n4) {
        float4 v = reinterpret_cast<const float4*>(src)[i];
        ushort4 o;
        o.x = f2bf(v.x); o.y = f2bf(v.y); o.z = f2bf(v.z); o.w = f2bf(v.w);
        reinterpret_cast<ushort4*>(dst)[i] = o;
    }
}

// ---------------- bf16 GEMM, C[M][N] = A[M][Kd] * B[N][Kd]^T ----------------
// 128x128 tile, BK=64, 4 waves (2x2), 16x16x32 MFMA, reg-staged LDS.
template <bool ADD_BIAS, bool SCALE>
__global__ __launch_bounds__(256) void gemm_bt(const unsigned short* __restrict__ A,
                                               const unsigned short* __restrict__ Bm,
                                               const float* __restrict__ bias,
                                               const float* __restrict__ scale_p,
                                               float* __restrict__ C, int M, int N, int Kd) {
    __shared__ unsigned short As[128 * 64];
    __shared__ unsigned short Bs[128 * 64];
    const int tid = threadIdx.x;
    const int w = tid >> 6, l = tid & 63;
    const int m0 = blockIdx.x * 128;
    const int n0 = blockIdx.y * 128;
    const int wm = w >> 1, wn = w & 1;
    const int lr = l & 15, lk = (l >> 4) * 8;

    f32x4 acc[4][4];
#pragma unroll
    for (int mi = 0; mi < 4; ++mi)
#pragma unroll
        for (int ni = 0; ni < 4; ++ni) acc[mi][ni] = (f32x4){0.f, 0.f, 0.f, 0.f};

    for (int k0 = 0; k0 < Kd; k0 += 64) {
#pragma unroll
        for (int i = 0; i < 4; ++i) {
            int fe = (i * 4 + w) * 512 + l * 8;   // flat bf16 elem in tile
            int r = fe >> 6, cc = fe & 63;
            int4 va = *reinterpret_cast<const int4*>(A + (size_t)(m0 + r) * Kd + k0 + cc);
            int4 vb = *reinterpret_cast<const int4*>(Bm + (size_t)(n0 + r) * Kd + k0 + cc);
            *reinterpret_cast<int4*>(&As[fe]) = va;
            *reinterpret_cast<int4*>(&Bs[fe]) = vb;
        }
        __syncthreads();
#pragma unroll
        for (int kk = 0; kk < 64; kk += 32) {
            bf16x8 af[4], bfr[4];
#pragma unroll
            for (int mi = 0; mi < 4; ++mi)
                af[mi] = *reinterpret_cast<const bf16x8*>(&As[(wm * 64 + mi * 16 + lr) * 64 + kk + lk]);
#pragma unroll
            for (int ni = 0; ni < 4; ++ni)
                bfr[ni] = *reinterpret_cast<const bf16x8*>(&Bs[(wn * 64 + ni * 16 + lr) * 64 + kk + lk]);
#pragma unroll
            for (int mi = 0; mi < 4; ++mi)
#pragma unroll
                for (int ni = 0; ni < 4; ++ni)
                    acc[mi][ni] = __builtin_amdgcn_mfma_f32_16x16x32_bf16(af[mi], bfr[ni], acc[mi][ni], 0, 0, 0);
        }
        __syncthreads();
    }

    float sc = SCALE ? *scale_p : 1.0f;
#pragma unroll
    for (int mi = 0; mi < 4; ++mi) {
        int row = m0 + wm * 64 + mi * 16 + (l >> 4) * 4;
#pragma unroll
        for (int ni = 0; ni < 4; ++ni) {
            int col = n0 + wn * 64 + ni * 16 + lr;
            float bv = ADD_BIAS ? bias[col] : 0.0f;
#pragma unroll
            for (int j = 0; j < 4; ++j) {
                float v = acc[mi][ni][j] + bv;
                if (SCALE) v *= sc;
                C[(size_t)(row + j) * N + col] = v;
            }
        }
    }
}

// ---------------- per-step oscillator math ----------------
struct Step {
    float alpha, dr, di, cs, sn, g, beta;
};
template <bool FULL>
static __device__ __forceinline__ Step compute_step(const float* __restrict__ p, float pos) {
    Step s;
    float a_raw = p[0];
    float o_raw = p[K_];
    float phi   = p[2 * K_];
    float al    = p[3 * K_];
    float A     = AMP_MAX * sigm(a_raw);
    float omega = softplusf_(o_raw);
    float alpha = sigm(al + GATE_BIAS);
    float angle = omega * pos + phi;
    float sn, cs;
    sincosf(angle, &sn, &cs);
    float oma = 1.0f - alpha;
    s.alpha = alpha;
    s.dr = oma * A * cs;
    s.di = oma * A * sn;
    s.cs = cs;
    s.sn = sn;
    if (FULL) {
        s.g    = sigm(p[4 * K_]);
        s.beta = sigm(p[5 * K_]);
    }
    return s;
}

// ---------------- scan stage 1: chunk summaries ----------------
// grid: (chunk=16, kgroup=16, b=4); block: 256 = 16 channels x 16 sub-chunks of 16 steps
__global__ __launch_bounds__(256) void scan_sum_kernel(const float* __restrict__ raw,
                                                       float* __restrict__ sA,
                                                       float* __restrict__ sR,
                                                       float* __restrict__ sI) {
    const int tid = threadIdx.x;
    const int c = tid & 15, t = tid >> 4;
    const int chunk = blockIdx.x, kg = blockIdx.y, b = blockIdx.z;
    const int k = kg * 16 + c;
    const int n0 = chunk * 256 + t * 16;
    const float* base = raw + (size_t)(b * N_ + n0) * P_ + k;

    float aP = 1.0f, rR = 0.0f, rI = 0.0f;
#pragma unroll
    for (int j = 0; j < 16; ++j) {
        Step s = compute_step<false>(base + (size_t)j * P_, log1pf((float)(n0 + j)));
        aP *= s.alpha;
        rR = s.alpha * rR + s.dr;
        rI = s.alpha * rI + s.di;
    }
    __shared__ float lA[256], lR[256], lI[256];
    lA[c * 16 + t] = aP;
    lR[c * 16 + t] = rR;
    lI[c * 16 + t] = rI;
    __syncthreads();
    if (tid < 16) {
        float a = 1.0f, r = 0.0f, im = 0.0f;
        for (int tt = 0; tt < 16; ++tt) {
            float at = lA[tid * 16 + tt];
            r  = at * r  + lR[tid * 16 + tt];
            im = at * im + lI[tid * 16 + tt];
            a *= at;
        }
        int chan = b * K_ + kg * 16 + tid;
        sA[chunk * 1024 + chan] = a;
        sR[chunk * 1024 + chan] = r;
        sI[chunk * 1024 + chan] = im;
    }
}

// ---------------- scan stage 2: apply + postprocess -> rho (bf16) ----------------
__global__ __launch_bounds__(256) void scan_apply_kernel(const float* __restrict__ raw,
                                                         const float* __restrict__ sA,
                                                         const float* __restrict__ sR,
                                                         const float* __restrict__ sI,
                                                         unsigned short* __restrict__ rho) {
    const int tid = threadIdx.x;
    const int c = tid & 15, t = tid >> 4;
    const int chunk = blockIdx.x, kg = blockIdx.y, b = blockIdx.z;
    const int k = kg * 16 + c;
    const int n0 = chunk * 256 + t * 16;
    const float* base = raw + (size_t)(b * N_ + n0) * P_ + k;

    // chunk-prefix (exclusive) for channel handled by lanes tid<16
    float pR = 0.0f, pI = 0.0f;
    if (tid < 16) {
        int chan = b * K_ + kg * 16 + tid;
        for (int ch = 0; ch < chunk; ++ch) {
            float a = sA[ch * 1024 + chan];
            pR = a * pR + sR[ch * 1024 + chan];
            pI = a * pI + sI[ch * 1024 + chan];
        }
    }
    // local pass 1
    float aP = 1.0f, rR = 0.0f, rI = 0.0f;
#pragma unroll
    for (int j = 0; j < 16; ++j) {
        Step s = compute_step<false>(base + (size_t)j * P_, log1pf((float)(n0 + j)));
        aP *= s.alpha;
        rR = s.alpha * rR + s.dr;
        rI = s.alpha * rI + s.di;
    }
    __shared__ float lA[256], lR[256], lI[256], pTR[256], pTI[256];
    lA[c * 16 + t] = aP;
    lR[c * 16 + t] = rR;
    lI[c * 16 + t] = rI;
    __syncthreads();
    if (tid < 16) {
        float r = pR, im = pI;
        for (int tt = 0; tt < 16; ++tt) {
            pTR[tid * 16 + tt] = r;
            pTI[tid * 16 + tt] = im;
            float at = lA[tid * 16 + tt];
            r  = at * r  + lR[tid * 16 + tt];
            im = at * im + lI[tid * 16 + tt];
        }
    }
    __syncthreads();
    // pass 2: seeded re-walk + postprocess
    float r = pTR[c * 16 + t], im = pTI[c * 16 + t];
    unsigned short* orow = rho + (size_t)(b * N_ + n0) * DK2_ + k;
#pragma unroll
    for (int j = 0; j < 16; ++j) {
        Step s = compute_step<true>(base + (size_t)j * P_, log1pf((float)(n0 + j)));
        r  = s.alpha * r  + s.dr;
        im = s.alpha * im + s.di;
        float readout = r * s.cs + im * s.sn;
        float r2 = r  - s.beta * readout * s.cs;
        float i3 = im - s.beta * readout * s.sn;
        float mod = sqrtf(r2 * r2 + i3 * i3 + 1e-8f);
        float scl = fmaxf(mod, 1.0f);
        float rr = r2 / scl, ri = i3 / scl;
        float rho_re = rr * s.cs + ri * s.sn;
        float rho_im = -rr * s.sn + ri * s.cs;
        orow[(size_t)j * DK2_]      = f2bf(s.g * rho_re);
        orow[(size_t)j * DK2_ + K_] = f2bf(s.g * rho_im);
    }
}

extern "C" void kernel_launch(void* const* d_in, const int* in_sizes, int n_in,
                              void* d_out, int out_size, void* d_ws, size_t ws_size,
                              hipStream_t stream) {
    const float* x  = (const float*)d_in[0];
    const float* Wp = (const float*)d_in[1];
    const float* bp = (const float*)d_in[2];
    const float* Wr = (const float*)d_in[3];
    const float* rs = (const float*)d_in[4];
    float* out = (float*)d_out;
    char* ws = (char*)d_ws;

    // workspace layout (bytes)
    float* raw = (float*)ws;                                     // 16384*1536*4 = 100,663,296
    unsigned short* xb  = (unsigned short*)(ws + 100663296);     // 33,554,432
    unsigned short* wpb = (unsigned short*)(ws + 134217728);     // 3,145,728
    unsigned short* wrb = (unsigned short*)(ws + 137363456);     // 1,048,576
    float* sA = (float*)(ws + 138412032);                        // 65,536
    float* sR = (float*)(ws + 138477568);                        // 65,536
    float* sI = (float*)(ws + 138543104);                        // 65,536
    unsigned short* rho = xb;  // alias: x_bf16 dead after GEMM1, rho written later

    cvt_kernel<<<16384, 256, 0, stream>>>(x, xb, M_ * D_ / 4);
    cvt_kernel<<<1536, 256, 0, stream>>>(Wp, wpb, P_ * D_ / 4);
    cvt_kernel<<<512, 256, 0, stream>>>(Wr, wrb, D_ * DK2_ / 4);

    gemm_bt<true, false><<<dim3(M_ / 128, P_ / 128), 256, 0, stream>>>(
        xb, wpb, bp, nullptr, raw, M_, P_, D_);

    scan_sum_kernel<<<dim3(16, 16, 4), 256, 0, stream>>>(raw, sA, sR, sI);
    scan_apply_kernel<<<dim3(16, 16, 4), 256, 0, stream>>>(raw, sA, sR, sI, rho);

    gemm_bt<false, true><<<dim3(M_ / 128, D_ / 128), 256, 0, stream>>>(
        rho, wrb, nullptr, rs, out, M_, D_, DK2_);
}

// Round 2
// 195.226 us; speedup vs baseline: 1.2970x; 1.2970x over previous
//
#include <hip/hip_runtime.h>
#include <hip/hip_bf16.h>
#include <cstdint>
#include <cstddef>

#define B_ 4
#define N_ 4096
#define D_ 1024
#define K_ 256
#define M_ (B_ * N_)          // 16384 rows
#define P_ (6 * K_)           // 1536 proj cols
#define DK2_ (2 * K_)         // 512 rho cols

static __device__ __forceinline__ float sigm(float x) {
    return 1.0f / (1.0f + __expf(-x));
}
static __device__ __forceinline__ float softplusf_(float x) {
    return fmaxf(x, 0.0f) + __logf(1.0f + __expf(-fabsf(x)));
}
static __device__ __forceinline__ unsigned short f2bf(float f) {
    uint32_t u = __float_as_uint(f);
    uint32_t r = (u + 0x7FFFu + ((u >> 16) & 1u)) >> 16;
    return (unsigned short)r;
}

#define GATE_BIAS 0.6190392084062235f
#define AMP_MAX 3.0f

typedef __attribute__((ext_vector_type(8))) __bf16 bf16x8;
typedef __attribute__((ext_vector_type(4))) float f32x4;

// async global->LDS, 16B per lane; lds dest must be wave-uniform base (HW adds lane*16)
static __device__ __forceinline__ void gload_lds16(const unsigned short* g, unsigned short* l) {
    __builtin_amdgcn_global_load_lds(
        (const __attribute__((address_space(1))) void*)g,
        (__attribute__((address_space(3))) void*)l, 16, 0, 0);
}

// ---------------- fp32 -> bf16 convert ----------------
__global__ __launch_bounds__(256) void cvt_kernel(const float* __restrict__ src,
                                                  unsigned short* __restrict__ dst, int n4) {
    int i = blockIdx.x * 256 + threadIdx.x;
    if (i < n4) {
        float4 v = reinterpret_cast<const float4*>(src)[i];
        ushort4 o;
        o.x = f2bf(v.x); o.y = f2bf(v.y); o.z = f2bf(v.z); o.w = f2bf(v.w);
        reinterpret_cast<ushort4*>(dst)[i] = o;
    }
}

// ---------------- bf16 GEMM, C[M][N] = A[M][Kd] * B[N][Kd]^T ----------------
// 128x128 tile, BK=64, 4 waves (2x2), 16x16x32 MFMA, global_load_lds staging (m97).
template <bool ADD_BIAS, bool SCALE>
__global__ __launch_bounds__(256) void gemm_bt(const unsigned short* __restrict__ A,
                                               const unsigned short* __restrict__ Bm,
                                               const float* __restrict__ bias,
                                               const float* __restrict__ scale_p,
                                               float* __restrict__ C, int M, int N, int Kd) {
    __shared__ unsigned short As[128 * 64];
    __shared__ unsigned short Bs[128 * 64];
    const int tid = threadIdx.x;
    const int w = tid >> 6, l = tid & 63;
    const int m0 = blockIdx.x * 128;
    const int n0 = blockIdx.y * 128;
    const int wm = w >> 1, wn = w & 1;
    const int lr = l & 15, lk = (l >> 4) * 8;

    f32x4 acc[4][4];
#pragma unroll
    for (int mi = 0; mi < 4; ++mi)
#pragma unroll
        for (int ni = 0; ni < 4; ++ni) acc[mi][ni] = (f32x4){0.f, 0.f, 0.f, 0.f};

    // per-lane source row/col within tile for staging: 8 lanes cover one 64-elem row
    const int sr_base = l >> 3;          // + (i*4+w)*8
    const int scc = (l & 7) * 8;

    for (int k0 = 0; k0 < Kd; k0 += 64) {
#pragma unroll
        for (int i = 0; i < 4; ++i) {
            int rowblk = (i * 4 + w) * 8;                // tile row of this wave-chunk
            int r = rowblk + sr_base;
            gload_lds16(A + (size_t)(m0 + r) * Kd + k0 + scc, &As[(i * 4 + w) * 512]);
            gload_lds16(Bm + (size_t)(n0 + r) * Kd + k0 + scc, &Bs[(i * 4 + w) * 512]);
        }
        __syncthreads();
#pragma unroll
        for (int kk = 0; kk < 64; kk += 32) {
            bf16x8 af[4], bfr[4];
#pragma unroll
            for (int mi = 0; mi < 4; ++mi)
                af[mi] = *reinterpret_cast<const bf16x8*>(&As[(wm * 64 + mi * 16 + lr) * 64 + kk + lk]);
#pragma unroll
            for (int ni = 0; ni < 4; ++ni)
                bfr[ni] = *reinterpret_cast<const bf16x8*>(&Bs[(wn * 64 + ni * 16 + lr) * 64 + kk + lk]);
#pragma unroll
            for (int mi = 0; mi < 4; ++mi)
#pragma unroll
                for (int ni = 0; ni < 4; ++ni)
                    acc[mi][ni] = __builtin_amdgcn_mfma_f32_16x16x32_bf16(af[mi], bfr[ni], acc[mi][ni], 0, 0, 0);
        }
        __syncthreads();
    }

    float sc = SCALE ? *scale_p : 1.0f;
#pragma unroll
    for (int mi = 0; mi < 4; ++mi) {
        int row = m0 + wm * 64 + mi * 16 + (l >> 4) * 4;
#pragma unroll
        for (int ni = 0; ni < 4; ++ni) {
            int col = n0 + wn * 64 + ni * 16 + lr;
            float bv = ADD_BIAS ? bias[col] : 0.0f;
#pragma unroll
            for (int j = 0; j < 4; ++j) {
                float v = acc[mi][ni][j] + bv;
                if (SCALE) v *= sc;
                C[(size_t)(row + j) * N + col] = v;
            }
        }
    }
}

// ---------------- per-step oscillator math ----------------
struct Step {
    float alpha, dr, di, cs, sn, g, beta;
};
template <bool FULL>
static __device__ __forceinline__ Step compute_step(const float* __restrict__ p, float pos) {
    Step s;
    float a_raw = p[0];
    float o_raw = p[K_];
    float phi   = p[2 * K_];
    float al    = p[3 * K_];
    float A     = AMP_MAX * sigm(a_raw);
    float omega = softplusf_(o_raw);
    float alpha = sigm(al + GATE_BIAS);
    float angle = omega * pos + phi;
    float sn, cs;
    __sincosf(angle, &sn, &cs);
    float oma = 1.0f - alpha;
    s.alpha = alpha;
    s.dr = oma * A * cs;
    s.di = oma * A * sn;
    s.cs = cs;
    s.sn = sn;
    if (FULL) {
        s.g    = sigm(p[4 * K_]);
        s.beta = sigm(p[5 * K_]);
    }
    return s;
}

// ---------------- scan stage 1: chunk summaries ----------------
// grid: (chunk=16, kgroup=16, b=4); block: 256 = 16 channels x 16 sub-chunks of 16 steps
__global__ __launch_bounds__(256) void scan_sum_kernel(const float* __restrict__ raw,
                                                       float* __restrict__ sA,
                                                       float* __restrict__ sR,
                                                       float* __restrict__ sI) {
    const int tid = threadIdx.x;
    const int c = tid & 15, t = tid >> 4;
    const int chunk = blockIdx.x, kg = blockIdx.y, b = blockIdx.z;
    const int k = kg * 16 + c;
    const int n0 = chunk * 256 + t * 16;
    const float* base = raw + (size_t)(b * N_ + n0) * P_ + k;

    float aP = 1.0f, rR = 0.0f, rI = 0.0f;
#pragma unroll
    for (int j = 0; j < 16; ++j) {
        Step s = compute_step<false>(base + (size_t)j * P_, __logf((float)(n0 + j + 1)));
        aP *= s.alpha;
        rR = s.alpha * rR + s.dr;
        rI = s.alpha * rI + s.di;
    }
    __shared__ float lA[256], lR[256], lI[256];
    lA[c * 16 + t] = aP;
    lR[c * 16 + t] = rR;
    lI[c * 16 + t] = rI;
    __syncthreads();
    if (tid < 16) {
        float a = 1.0f, r = 0.0f, im = 0.0f;
        for (int tt = 0; tt < 16; ++tt) {
            float at = lA[tid * 16 + tt];
            r  = at * r  + lR[tid * 16 + tt];
            im = at * im + lI[tid * 16 + tt];
            a *= at;
        }
        int chan = b * K_ + kg * 16 + tid;
        sA[chunk * 1024 + chan] = a;
        sR[chunk * 1024 + chan] = r;
        sI[chunk * 1024 + chan] = im;
    }
}

// ---------------- scan stage 2: apply + postprocess -> rho (bf16) ----------------
__global__ __launch_bounds__(256) void scan_apply_kernel(const float* __restrict__ raw,
                                                         const float* __restrict__ sA,
                                                         const float* __restrict__ sR,
                                                         const float* __restrict__ sI,
                                                         unsigned short* __restrict__ rho) {
    const int tid = threadIdx.x;
    const int c = tid & 15, t = tid >> 4;
    const int chunk = blockIdx.x, kg = blockIdx.y, b = blockIdx.z;
    const int k = kg * 16 + c;
    const int n0 = chunk * 256 + t * 16;
    const float* base = raw + (size_t)(b * N_ + n0) * P_ + k;

    // chunk-prefix (exclusive) for channel handled by lanes tid<16
    float pR = 0.0f, pI = 0.0f;
    if (tid < 16) {
        int chan = b * K_ + kg * 16 + tid;
        for (int ch = 0; ch < chunk; ++ch) {
            float a = sA[ch * 1024 + chan];
            pR = a * pR + sR[ch * 1024 + chan];
            pI = a * pI + sI[ch * 1024 + chan];
        }
    }
    // local pass 1
    float aP = 1.0f, rR = 0.0f, rI = 0.0f;
#pragma unroll
    for (int j = 0; j < 16; ++j) {
        Step s = compute_step<false>(base + (size_t)j * P_, __logf((float)(n0 + j + 1)));
        aP *= s.alpha;
        rR = s.alpha * rR + s.dr;
        rI = s.alpha * rI + s.di;
    }
    __shared__ float lA[256], lR[256], lI[256], pTR[256], pTI[256];
    lA[c * 16 + t] = aP;
    lR[c * 16 + t] = rR;
    lI[c * 16 + t] = rI;
    __syncthreads();
    if (tid < 16) {
        float r = pR, im = pI;
        for (int tt = 0; tt < 16; ++tt) {
            pTR[tid * 16 + tt] = r;
            pTI[tid * 16 + tt] = im;
            float at = lA[tid * 16 + tt];
            r  = at * r  + lR[tid * 16 + tt];
            im = at * im + lI[tid * 16 + tt];
        }
    }
    __syncthreads();
    // pass 2: seeded re-walk + postprocess
    float r = pTR[c * 16 + t], im = pTI[c * 16 + t];
    unsigned short* orow = rho + (size_t)(b * N_ + n0) * DK2_ + k;
#pragma unroll
    for (int j = 0; j < 16; ++j) {
        Step s = compute_step<true>(base + (size_t)j * P_, __logf((float)(n0 + j + 1)));
        r  = s.alpha * r  + s.dr;
        im = s.alpha * im + s.di;
        float readout = r * s.cs + im * s.sn;
        float r2 = r  - s.beta * readout * s.cs;
        float i3 = im - s.beta * readout * s.sn;
        float mod = __fsqrt_rn(r2 * r2 + i3 * i3 + 1e-8f);
        float scl = fmaxf(mod, 1.0f);
        float inv = 1.0f / scl;
        float rr = r2 * inv, ri = i3 * inv;
        float rho_re = rr * s.cs + ri * s.sn;
        float rho_im = -rr * s.sn + ri * s.cs;
        orow[(size_t)j * DK2_]      = f2bf(s.g * rho_re);
        orow[(size_t)j * DK2_ + K_] = f2bf(s.g * rho_im);
    }
}

extern "C" void kernel_launch(void* const* d_in, const int* in_sizes, int n_in,
                              void* d_out, int out_size, void* d_ws, size_t ws_size,
                              hipStream_t stream) {
    const float* x  = (const float*)d_in[0];
    const float* Wp = (const float*)d_in[1];
    const float* bp = (const float*)d_in[2];
    const float* Wr = (const float*)d_in[3];
    const float* rs = (const float*)d_in[4];
    float* out = (float*)d_out;
    char* ws = (char*)d_ws;

    // workspace layout (bytes)
    float* raw = (float*)ws;                                     // 16384*1536*4 = 100,663,296
    unsigned short* xb  = (unsigned short*)(ws + 100663296);     // 33,554,432
    unsigned short* wpb = (unsigned short*)(ws + 134217728);     // 3,145,728
    unsigned short* wrb = (unsigned short*)(ws + 137363456);     // 1,048,576
    float* sA = (float*)(ws + 138412032);                        // 65,536
    float* sR = (float*)(ws + 138477568);                        // 65,536
    float* sI = (float*)(ws + 138543104);                        // 65,536
    unsigned short* rho = xb;  // alias: x_bf16 dead after GEMM1, rho written later

    cvt_kernel<<<16384, 256, 0, stream>>>(x, xb, M_ * D_ / 4);
    cvt_kernel<<<1536, 256, 0, stream>>>(Wp, wpb, P_ * D_ / 4);
    cvt_kernel<<<512, 256, 0, stream>>>(Wr, wrb, D_ * DK2_ / 4);

    gemm_bt<true, false><<<dim3(M_ / 128, P_ / 128), 256, 0, stream>>>(
        xb, wpb, bp, nullptr, raw, M_, P_, D_);

    scan_sum_kernel<<<dim3(16, 16, 4), 256, 0, stream>>>(raw, sA, sR, sI);
    scan_apply_kernel<<<dim3(16, 16, 4), 256, 0, stream>>>(raw, sA, sR, sI, rho);

    gemm_bt<false, true><<<dim3(M_ / 128, D_ / 128), 256, 0, stream>>>(
        rho, wrb, nullptr, rs, out, M_, D_, DK2_);
}

// Round 3
// 190.259 us; speedup vs baseline: 1.3308x; 1.0261x over previous
//
#include <hip/hip_runtime.h>
#include <hip/hip_bf16.h>
#include <cstdint>
#include <cstddef>

#define B_ 4
#define N_ 4096
#define D_ 1024
#define K_ 256
#define M_ (B_ * N_)          // 16384 rows
#define P_ (6 * K_)           // 1536 proj cols
#define DK2_ (2 * K_)         // 512 rho cols

static __device__ __forceinline__ float sigm(float x) {
    return 1.0f / (1.0f + __expf(-x));
}
static __device__ __forceinline__ float softplusf_(float x) {
    return fmaxf(x, 0.0f) + __logf(1.0f + __expf(-fabsf(x)));
}
static __device__ __forceinline__ unsigned short f2bf(float f) {
    uint32_t u = __float_as_uint(f);
    uint32_t r = (u + 0x7FFFu + ((u >> 16) & 1u)) >> 16;
    return (unsigned short)r;
}

#define GATE_BIAS 0.6190392084062235f
#define AMP_MAX 3.0f

typedef __attribute__((ext_vector_type(8))) __bf16 bf16x8;
typedef __attribute__((ext_vector_type(4))) float f32x4;

// async global->LDS, 16B per lane; lds dest must be wave-uniform base (HW adds lane*16)
static __device__ __forceinline__ void gload_lds16(const unsigned short* g, unsigned short* l) {
    __builtin_amdgcn_global_load_lds(
        (const __attribute__((address_space(1))) void*)g,
        (__attribute__((address_space(3))) void*)l, 16, 0, 0);
}

// ---------------- fp32 -> bf16 convert ----------------
__global__ __launch_bounds__(256) void cvt_kernel(const float* __restrict__ src,
                                                  unsigned short* __restrict__ dst, int n4) {
    int i = blockIdx.x * 256 + threadIdx.x;
    if (i < n4) {
        float4 v = reinterpret_cast<const float4*>(src)[i];
        ushort4 o;
        o.x = f2bf(v.x); o.y = f2bf(v.y); o.z = f2bf(v.z); o.w = f2bf(v.w);
        reinterpret_cast<ushort4*>(dst)[i] = o;
    }
}

// ---------------- bf16 GEMM, C[M][N] = A[M][Kd] * B[N][Kd]^T ----------------
// 128x256 tile, BK=64, 8 waves (2Mx4N), 3 LDS buffers, counted-vmcnt pipeline,
// XOR-swizzled LDS via pre-swizzled global source (both-sides, rule 21).
// Iter t: vmcnt(6) [tile t+1 in flight]; s_barrier; stage(t+2 -> buf[(t+2)%3]);
//         compute tile t from buf[t%3]. Race-free: staged buffer last read 2 barriers ago.

static __device__ __forceinline__ void stage_tile(const unsigned short* __restrict__ A,
                                                  const unsigned short* __restrict__ Bm,
                                                  unsigned short* Asq, unsigned short* Bsq,
                                                  int m0, int n0, int Kd, int k0,
                                                  int tid, int w) {
    const int rw = tid >> 3;      // 0..63
    const int slot = tid & 7;
#pragma unroll
    for (int r = 0; r < 2; ++r) {
        int row = r * 64 + rw;
        int col = k0 + ((slot ^ (row & 7)) << 3);
        gload_lds16(A + (size_t)(m0 + row) * Kd + col, Asq + r * 4096 + w * 512);
    }
#pragma unroll
    for (int r = 0; r < 4; ++r) {
        int row = r * 64 + rw;
        int col = k0 + ((slot ^ (row & 7)) << 3);
        gload_lds16(Bm + (size_t)(n0 + row) * Kd + col, Bsq + r * 4096 + w * 512);
    }
}

template <bool ADD_BIAS, bool SCALE>
__global__ __launch_bounds__(512, 2) void gemm_bt(const unsigned short* __restrict__ A,
                                                  const unsigned short* __restrict__ Bm,
                                                  const float* __restrict__ bias,
                                                  const float* __restrict__ scale_p,
                                                  float* __restrict__ C, int M, int N, int Kd) {
    __shared__ unsigned short As[3][128 * 64];
    __shared__ unsigned short Bs[3][256 * 64];
    const int tid = threadIdx.x;
    const int w = tid >> 6, l = tid & 63;
    const int m0 = blockIdx.x * 128;
    const int n0 = blockIdx.y * 256;
    const int wm = w >> 2, wn = w & 3;         // 2 x 4 wave grid
    const int lr = l & 15, lk = (l >> 4) * 8;
    const int nt = Kd >> 6;

    f32x4 acc[4][4];
#pragma unroll
    for (int mi = 0; mi < 4; ++mi)
#pragma unroll
        for (int ni = 0; ni < 4; ++ni) acc[mi][ni] = (f32x4){0.f, 0.f, 0.f, 0.f};

    // prologue: stage tiles 0 and 1
    stage_tile(A, Bm, As[0], Bs[0], m0, n0, Kd, 0, tid, w);
    stage_tile(A, Bm, As[1], Bs[1], m0, n0, Kd, 64, tid, w);

    for (int t = 0; t < nt; ++t) {
        const int q = t % 3;
        if (t < nt - 1) {
            asm volatile("s_waitcnt vmcnt(6)" ::: "memory");
        } else {
            asm volatile("s_waitcnt vmcnt(0)" ::: "memory");
        }
        __builtin_amdgcn_s_barrier();
        if (t + 2 < nt) {
            int q2 = (t + 2) % 3;
            stage_tile(A, Bm, As[q2], Bs[q2], m0, n0, Kd, (t + 2) * 64, tid, w);
        }
#pragma unroll
        for (int kk = 0; kk < 64; kk += 32) {
            bf16x8 af[4], bfr[4];
#pragma unroll
            for (int mi = 0; mi < 4; ++mi) {
                int ar = wm * 64 + mi * 16 + lr;
                af[mi] = *reinterpret_cast<const bf16x8*>(
                    &As[q][ar * 64 + ((((kk + lk) >> 3) ^ (ar & 7)) << 3)]);
            }
#pragma unroll
            for (int ni = 0; ni < 4; ++ni) {
                int br = wn * 64 + ni * 16 + lr;
                bfr[ni] = *reinterpret_cast<const bf16x8*>(
                    &Bs[q][br * 64 + ((((kk + lk) >> 3) ^ (br & 7)) << 3)]);
            }
            __builtin_amdgcn_s_setprio(1);
#pragma unroll
            for (int mi = 0; mi < 4; ++mi)
#pragma unroll
                for (int ni = 0; ni < 4; ++ni)
                    acc[mi][ni] = __builtin_amdgcn_mfma_f32_16x16x32_bf16(af[mi], bfr[ni], acc[mi][ni], 0, 0, 0);
            __builtin_amdgcn_s_setprio(0);
        }
    }

    float sc = SCALE ? *scale_p : 1.0f;
#pragma unroll
    for (int mi = 0; mi < 4; ++mi) {
        int row = m0 + wm * 64 + mi * 16 + (l >> 4) * 4;
#pragma unroll
        for (int ni = 0; ni < 4; ++ni) {
            int col = n0 + wn * 64 + ni * 16 + lr;
            float bv = ADD_BIAS ? bias[col] : 0.0f;
#pragma unroll
            for (int j = 0; j < 4; ++j) {
                float v = acc[mi][ni][j] + bv;
                if (SCALE) v *= sc;
                C[(size_t)(row + j) * N + col] = v;
            }
        }
    }
}

// ---------------- per-step oscillator math ----------------
struct Step {
    float alpha, dr, di, cs, sn, g, beta;
};
template <bool FULL>
static __device__ __forceinline__ Step compute_step(const float* __restrict__ p, float pos) {
    Step s;
    float a_raw = p[0];
    float o_raw = p[K_];
    float phi   = p[2 * K_];
    float al    = p[3 * K_];
    float A     = AMP_MAX * sigm(a_raw);
    float omega = softplusf_(o_raw);
    float alpha = sigm(al + GATE_BIAS);
    float angle = omega * pos + phi;
    float sn, cs;
    __sincosf(angle, &sn, &cs);
    float oma = 1.0f - alpha;
    s.alpha = alpha;
    s.dr = oma * A * cs;
    s.di = oma * A * sn;
    s.cs = cs;
    s.sn = sn;
    if (FULL) {
        s.g    = sigm(p[4 * K_]);
        s.beta = sigm(p[5 * K_]);
    }
    return s;
}

// ---------------- scan stage 1: chunk summaries ----------------
// grid: (chunk=16, kgroup=16, b=4); block: 256 = 16 channels x 16 sub-chunks of 16 steps
__global__ __launch_bounds__(256) void scan_sum_kernel(const float* __restrict__ raw,
                                                       float* __restrict__ sA,
                                                       float* __restrict__ sR,
                                                       float* __restrict__ sI) {
    const int tid = threadIdx.x;
    const int c = tid & 15, t = tid >> 4;
    const int chunk = blockIdx.x, kg = blockIdx.y, b = blockIdx.z;
    const int k = kg * 16 + c;
    const int n0 = chunk * 256 + t * 16;
    const float* base = raw + (size_t)(b * N_ + n0) * P_ + k;

    float aP = 1.0f, rR = 0.0f, rI = 0.0f;
#pragma unroll
    for (int j = 0; j < 16; ++j) {
        Step s = compute_step<false>(base + (size_t)j * P_, __logf((float)(n0 + j + 1)));
        aP *= s.alpha;
        rR = s.alpha * rR + s.dr;
        rI = s.alpha * rI + s.di;
    }
    __shared__ float lA[256], lR[256], lI[256];
    lA[c * 16 + t] = aP;
    lR[c * 16 + t] = rR;
    lI[c * 16 + t] = rI;
    __syncthreads();
    if (tid < 16) {
        float a = 1.0f, r = 0.0f, im = 0.0f;
        for (int tt = 0; tt < 16; ++tt) {
            float at = lA[tid * 16 + tt];
            r  = at * r  + lR[tid * 16 + tt];
            im = at * im + lI[tid * 16 + tt];
            a *= at;
        }
        int chan = b * K_ + kg * 16 + tid;
        sA[chunk * 1024 + chan] = a;
        sR[chunk * 1024 + chan] = r;
        sI[chunk * 1024 + chan] = im;
    }
}

// ---------------- scan stage 2: apply + postprocess -> rho (bf16) ----------------
__global__ __launch_bounds__(256) void scan_apply_kernel(const float* __restrict__ raw,
                                                         const float* __restrict__ sA,
                                                         const float* __restrict__ sR,
                                                         const float* __restrict__ sI,
                                                         unsigned short* __restrict__ rho) {
    const int tid = threadIdx.x;
    const int c = tid & 15, t = tid >> 4;
    const int chunk = blockIdx.x, kg = blockIdx.y, b = blockIdx.z;
    const int k = kg * 16 + c;
    const int n0 = chunk * 256 + t * 16;
    const float* base = raw + (size_t)(b * N_ + n0) * P_ + k;

    // chunk-prefix (exclusive) for channel handled by lanes tid<16
    float pR = 0.0f, pI = 0.0f;
    if (tid < 16) {
        int chan = b * K_ + kg * 16 + tid;
        for (int ch = 0; ch < chunk; ++ch) {
            float a = sA[ch * 1024 + chan];
            pR = a * pR + sR[ch * 1024 + chan];
            pI = a * pI + sI[ch * 1024 + chan];
        }
    }
    // local pass 1
    float aP = 1.0f, rR = 0.0f, rI = 0.0f;
#pragma unroll
    for (int j = 0; j < 16; ++j) {
        Step s = compute_step<false>(base + (size_t)j * P_, __logf((float)(n0 + j + 1)));
        aP *= s.alpha;
        rR = s.alpha * rR + s.dr;
        rI = s.alpha * rI + s.di;
    }
    __shared__ float lA[256], lR[256], lI[256], pTR[256], pTI[256];
    lA[c * 16 + t] = aP;
    lR[c * 16 + t] = rR;
    lI[c * 16 + t] = rI;
    __syncthreads();
    if (tid < 16) {
        float r = pR, im = pI;
        for (int tt = 0; tt < 16; ++tt) {
            pTR[tid * 16 + tt] = r;
            pTI[tid * 16 + tt] = im;
            float at = lA[tid * 16 + tt];
            r  = at * r  + lR[tid * 16 + tt];
            im = at * im + lI[tid * 16 + tt];
        }
    }
    __syncthreads();
    // pass 2: seeded re-walk + postprocess
    float r = pTR[c * 16 + t], im = pTI[c * 16 + t];
    unsigned short* orow = rho + (size_t)(b * N_ + n0) * DK2_ + k;
#pragma unroll
    for (int j = 0; j < 16; ++j) {
        Step s = compute_step<true>(base + (size_t)j * P_, __logf((float)(n0 + j + 1)));
        r  = s.alpha * r  + s.dr;
        im = s.alpha * im + s.di;
        float readout = r * s.cs + im * s.sn;
        float r2 = r  - s.beta * readout * s.cs;
        float i3 = im - s.beta * readout * s.sn;
        float mod = __fsqrt_rn(r2 * r2 + i3 * i3 + 1e-8f);
        float scl = fmaxf(mod, 1.0f);
        float inv = 1.0f / scl;
        float rr = r2 * inv, ri = i3 * inv;
        float rho_re = rr * s.cs + ri * s.sn;
        float rho_im = -rr * s.sn + ri * s.cs;
        orow[(size_t)j * DK2_]      = f2bf(s.g * rho_re);
        orow[(size_t)j * DK2_ + K_] = f2bf(s.g * rho_im);
    }
}

extern "C" void kernel_launch(void* const* d_in, const int* in_sizes, int n_in,
                              void* d_out, int out_size, void* d_ws, size_t ws_size,
                              hipStream_t stream) {
    const float* x  = (const float*)d_in[0];
    const float* Wp = (const float*)d_in[1];
    const float* bp = (const float*)d_in[2];
    const float* Wr = (const float*)d_in[3];
    const float* rs = (const float*)d_in[4];
    float* out = (float*)d_out;
    char* ws = (char*)d_ws;

    // workspace layout (bytes)
    float* raw = (float*)ws;                                     // 16384*1536*4 = 100,663,296
    unsigned short* xb  = (unsigned short*)(ws + 100663296);     // 33,554,432
    unsigned short* wpb = (unsigned short*)(ws + 134217728);     // 3,145,728
    unsigned short* wrb = (unsigned short*)(ws + 137363456);     // 1,048,576
    float* sA = (float*)(ws + 138412032);                        // 65,536
    float* sR = (float*)(ws + 138477568);                        // 65,536
    float* sI = (float*)(ws + 138543104);                        // 65,536
    unsigned short* rho = xb;  // alias: x_bf16 dead after GEMM1, rho written later

    cvt_kernel<<<16384, 256, 0, stream>>>(x, xb, M_ * D_ / 4);
    cvt_kernel<<<1536, 256, 0, stream>>>(Wp, wpb, P_ * D_ / 4);
    cvt_kernel<<<512, 256, 0, stream>>>(Wr, wrb, D_ * DK2_ / 4);

    gemm_bt<true, false><<<dim3(M_ / 128, P_ / 256), 512, 0, stream>>>(
        xb, wpb, bp, nullptr, raw, M_, P_, D_);

    scan_sum_kernel<<<dim3(16, 16, 4), 256, 0, stream>>>(raw, sA, sR, sI);
    scan_apply_kernel<<<dim3(16, 16, 4), 256, 0, stream>>>(raw, sA, sR, sI, rho);

    gemm_bt<false, true><<<dim3(M_ / 128, D_ / 256), 512, 0, stream>>>(
        rho, wrb, nullptr, rs, out, M_, D_, DK2_);
}

// Round 5
// 172.635 us; speedup vs baseline: 1.4667x; 1.1021x over previous
//
#include <hip/hip_runtime.h>
#include <hip/hip_bf16.h>
#include <cstdint>
#include <cstddef>

#define B_ 4
#define N_ 4096
#define D_ 1024
#define K_ 256
#define M_ (B_ * N_)          // 16384 rows
#define P_ (6 * K_)           // 1536 proj cols
#define DK2_ (2 * K_)         // 512 rho cols

static __device__ __forceinline__ float sigm(float x) {
    return 1.0f / (1.0f + __expf(-x));
}
static __device__ __forceinline__ float softplusf_(float x) {
    return fmaxf(x, 0.0f) + __logf(1.0f + __expf(-fabsf(x)));
}
static __device__ __forceinline__ unsigned short f2bf(float f) {
    uint32_t u = __float_as_uint(f);
    uint32_t r = (u + 0x7FFFu + ((u >> 16) & 1u)) >> 16;
    return (unsigned short)r;
}

#define GATE_BIAS 0.6190392084062235f
#define AMP_MAX 3.0f

typedef __attribute__((ext_vector_type(8))) __bf16 bf16x8;
typedef __attribute__((ext_vector_type(4))) float f32x4;

// async global->LDS, 16B per lane; lds dest must be wave-uniform base (HW adds lane*16)
static __device__ __forceinline__ void gload_lds16(const unsigned short* g, unsigned short* l) {
    __builtin_amdgcn_global_load_lds(
        (const __attribute__((address_space(1))) void*)g,
        (__attribute__((address_space(3))) void*)l, 16, 0, 0);
}

// ---------------- fp32 -> bf16 convert ----------------
__global__ __launch_bounds__(256) void cvt_kernel(const float* __restrict__ src,
                                                  unsigned short* __restrict__ dst, int n4) {
    int i = blockIdx.x * 256 + threadIdx.x;
    if (i < n4) {
        float4 v = reinterpret_cast<const float4*>(src)[i];
        ushort4 o;
        o.x = f2bf(v.x); o.y = f2bf(v.y); o.z = f2bf(v.z); o.w = f2bf(v.w);
        reinterpret_cast<ushort4*>(dst)[i] = o;
    }
}

// ---------------- bf16 GEMM, C[M][N] = A[M][Kd] * B[N][Kd]^T ----------------
// 256x256 tile, BK=64, 8 waves (2M x 4N), wave tile 128x64, acc[8][4].
// 2 static dbufs, K-loop unrolled x2 with literal buffer names.
// 4 phases/tile; 16 MFMA/phase. Stage tile t+1 in phases 0 (A) and 1 (B).
// Drain protocol (race-free, round-3-proven): each wave executes vmcnt(0)
// in the LAST phase of tile t, BEFORE that phase's closing s_barrier; the
// first ds_read of tile t+1 is therefore after a barrier at which every
// wave has drained its staging loads. ds_reads of each phase are drained by
// lgkmcnt(0) before the phase-closing barrier, so staging into the other
// dbuf (>=1 barrier later) never races the reads.

// swizzled fragment read: row r, k-col kc (element units) from 256x64 tile
#define FRAG(BUF, r, kc) \
    (*reinterpret_cast<const bf16x8*>(&(BUF)[(size_t)(r) * 64 + (((((kc) >> 3) ^ ((r) & 7)) << 3))]))

template <bool ADD_BIAS, bool SCALE>
__global__ __launch_bounds__(512, 2) void gemm_bt(const unsigned short* __restrict__ A,
                                                  const unsigned short* __restrict__ Bm,
                                                  const float* __restrict__ bias,
                                                  const float* __restrict__ scale_p,
                                                  float* __restrict__ C, int M, int N, int Kd) {
    __shared__ unsigned short As0[256 * 64];
    __shared__ unsigned short Bs0[256 * 64];
    __shared__ unsigned short As1[256 * 64];
    __shared__ unsigned short Bs1[256 * 64];

    const int tid = threadIdx.x;
    const int w = tid >> 6, l = tid & 63;
    const int m0 = blockIdx.x * 256;
    const int n0 = blockIdx.y * 256;
    const int wm = w >> 2, wn = w & 3;         // 2 x 4 wave grid
    const int lr = l & 15, lk = (l >> 4) * 8;
    const int nt = Kd >> 6;                    // 16 (GEMM1) / 8 (GEMM2), always even

    // staging geometry: 512 threads, 2 loads per half-tile (128 rows x 64 cols)
    const int srow = tid >> 3;                 // 0..63
    const int sslot = tid & 7;
    const int wbase = tid & ~63;

    f32x4 acc[8][4];
#pragma unroll
    for (int mi = 0; mi < 8; ++mi)
#pragma unroll
        for (int ni = 0; ni < 4; ++ni) acc[mi][ni] = (f32x4){0.f, 0.f, 0.f, 0.f};

    // stage half h (0/1) of a 256x64 tile from src row0g, k-offset k0
#define STAGE_HALF(SRC, DST, ROW0G, K0, H)                                            \
    {                                                                                 \
        _Pragma("unroll") for (int j = 0; j < 2; ++j) {                               \
            int row = (H) * 128 + j * 64 + srow;                                      \
            int col = (K0) + ((sslot ^ (row & 7)) << 3);                              \
            gload_lds16((SRC) + (size_t)((ROW0G) + row) * Kd + col,                   \
                        (DST) + (size_t)(((H) * 1024 + j * 512 + wbase) * 8));        \
        }                                                                             \
    }

#define PHASE(CA, CB, KK, MIH, STAGE_CODE, TAIL_CODE)                                 \
    {                                                                                 \
        _Pragma("unroll") for (int f = 0; f < 4; ++f) {                               \
            int ar = wm * 128 + ((MIH) * 4 + f) * 16 + lr;                            \
            af[f] = FRAG(CA, ar, (KK) + lk);                                          \
        }                                                                             \
        if ((MIH) == 0) {                                                             \
            _Pragma("unroll") for (int f = 0; f < 4; ++f) {                           \
                int br = wn * 64 + f * 16 + lr;                                       \
                bfr[f] = FRAG(CB, br, (KK) + lk);                                     \
            }                                                                         \
        }                                                                             \
        STAGE_CODE;                                                                   \
        __builtin_amdgcn_s_barrier();                                                 \
        asm volatile("s_waitcnt lgkmcnt(0)" ::: "memory");                            \
        __builtin_amdgcn_sched_barrier(0);                                            \
        __builtin_amdgcn_s_setprio(1);                                                \
        _Pragma("unroll") for (int mi = 0; mi < 4; ++mi)                              \
            _Pragma("unroll") for (int ni = 0; ni < 4; ++ni)                          \
                acc[(MIH) * 4 + mi][ni] = __builtin_amdgcn_mfma_f32_16x16x32_bf16(    \
                    af[mi], bfr[ni], acc[(MIH) * 4 + mi][ni], 0, 0, 0);               \
        __builtin_amdgcn_s_setprio(0);                                                \
        TAIL_CODE;                                                                    \
        __builtin_amdgcn_s_barrier();                                                 \
    }

#define TILE_STEP(T, CA, CB, PA, PB)                                                  \
    {                                                                                 \
        const int knext = ((T) + 1) * 64;                                             \
        const bool do_stage = ((T) + 1 < nt);                                         \
        bf16x8 af[4], bfr[4];                                                         \
        PHASE(CA, CB, 0, 0,                                                           \
              if (do_stage) { STAGE_HALF(A, PA, m0, knext, 0);                        \
                              STAGE_HALF(A, PA, m0, knext, 1); },                     \
              {});                                                                    \
        PHASE(CA, CB, 0, 1,                                                           \
              if (do_stage) { STAGE_HALF(Bm, PB, n0, knext, 0);                       \
                              STAGE_HALF(Bm, PB, n0, knext, 1); },                    \
              {});                                                                    \
        PHASE(CA, CB, 32, 0, {}, {});                                                 \
        PHASE(CA, CB, 32, 1, {},                                                      \
              asm volatile("s_waitcnt vmcnt(0)" ::: "memory"));                       \
    }

    // prologue: stage tile 0 into dbuf0, drain, barrier
    STAGE_HALF(A, As0, m0, 0, 0);
    STAGE_HALF(A, As0, m0, 0, 1);
    STAGE_HALF(Bm, Bs0, n0, 0, 0);
    STAGE_HALF(Bm, Bs0, n0, 0, 1);
    asm volatile("s_waitcnt vmcnt(0)" ::: "memory");
    __builtin_amdgcn_s_barrier();

    for (int t = 0; t < nt; t += 2) {
        TILE_STEP(t, As0, Bs0, As1, Bs1);
        TILE_STEP(t + 1, As1, Bs1, As0, Bs0);
    }

    float sc = SCALE ? *scale_p : 1.0f;
#pragma unroll
    for (int mi = 0; mi < 8; ++mi) {
        int row = m0 + wm * 128 + mi * 16 + (l >> 4) * 4;
#pragma unroll
        for (int ni = 0; ni < 4; ++ni) {
            int col = n0 + wn * 64 + ni * 16 + lr;
            float bv = ADD_BIAS ? bias[col] : 0.0f;
#pragma unroll
            for (int j = 0; j < 4; ++j) {
                float v = acc[mi][ni][j] + bv;
                if (SCALE) v *= sc;
                C[(size_t)(row + j) * N + col] = v;
            }
        }
    }
#undef STAGE_HALF
#undef PHASE
#undef TILE_STEP
}

// ---------------- per-step oscillator math ----------------
struct Step {
    float alpha, dr, di, cs, sn, g, beta;
};
template <bool FULL>
static __device__ __forceinline__ Step compute_step(const float* __restrict__ p, float pos) {
    Step s;
    float a_raw = p[0];
    float o_raw = p[K_];
    float phi   = p[2 * K_];
    float al    = p[3 * K_];
    float A     = AMP_MAX * sigm(a_raw);
    float omega = softplusf_(o_raw);
    float alpha = sigm(al + GATE_BIAS);
    float angle = omega * pos + phi;
    float sn, cs;
    __sincosf(angle, &sn, &cs);
    float oma = 1.0f - alpha;
    s.alpha = alpha;
    s.dr = oma * A * cs;
    s.di = oma * A * sn;
    s.cs = cs;
    s.sn = sn;
    if (FULL) {
        s.g    = sigm(p[4 * K_]);
        s.beta = sigm(p[5 * K_]);
    }
    return s;
}

// ---------------- scan stage 1: chunk summaries ----------------
// grid: (chunk=16, kgroup=16, b=4); block: 256 = 16 channels x 16 sub-chunks of 16 steps
__global__ __launch_bounds__(256) void scan_sum_kernel(const float* __restrict__ raw,
                                                       float* __restrict__ sA,
                                                       float* __restrict__ sR,
                                                       float* __restrict__ sI) {
    const int tid = threadIdx.x;
    const int c = tid & 15, t = tid >> 4;
    const int chunk = blockIdx.x, kg = blockIdx.y, b = blockIdx.z;
    const int k = kg * 16 + c;
    const int n0 = chunk * 256 + t * 16;
    const float* base = raw + (size_t)(b * N_ + n0) * P_ + k;

    float aP = 1.0f, rR = 0.0f, rI = 0.0f;
#pragma unroll
    for (int j = 0; j < 16; ++j) {
        Step s = compute_step<false>(base + (size_t)j * P_, __logf((float)(n0 + j + 1)));
        aP *= s.alpha;
        rR = s.alpha * rR + s.dr;
        rI = s.alpha * rI + s.di;
    }
    __shared__ float lA[256], lR[256], lI[256];
    lA[c * 16 + t] = aP;
    lR[c * 16 + t] = rR;
    lI[c * 16 + t] = rI;
    __syncthreads();
    if (tid < 16) {
        float a = 1.0f, r = 0.0f, im = 0.0f;
        for (int tt = 0; tt < 16; ++tt) {
            float at = lA[tid * 16 + tt];
            r  = at * r  + lR[tid * 16 + tt];
            im = at * im + lI[tid * 16 + tt];
            a *= at;
        }
        int chan = b * K_ + kg * 16 + tid;
        sA[chunk * 1024 + chan] = a;
        sR[chunk * 1024 + chan] = r;
        sI[chunk * 1024 + chan] = im;
    }
}

// ---------------- scan stage 2: apply + postprocess -> rho (bf16) ----------------
__global__ __launch_bounds__(256) void scan_apply_kernel(const float* __restrict__ raw,
                                                         const float* __restrict__ sA,
                                                         const float* __restrict__ sR,
                                                         const float* __restrict__ sI,
                                                         unsigned short* __restrict__ rho) {
    const int tid = threadIdx.x;
    const int c = tid & 15, t = tid >> 4;
    const int chunk = blockIdx.x, kg = blockIdx.y, b = blockIdx.z;
    const int k = kg * 16 + c;
    const int n0 = chunk * 256 + t * 16;
    const float* base = raw + (size_t)(b * N_ + n0) * P_ + k;

    // chunk-prefix (exclusive) for channel handled by lanes tid<16
    float pR = 0.0f, pI = 0.0f;
    if (tid < 16) {
        int chan = b * K_ + kg * 16 + tid;
        for (int ch = 0; ch < chunk; ++ch) {
            float a = sA[ch * 1024 + chan];
            pR = a * pR + sR[ch * 1024 + chan];
            pI = a * pI + sI[ch * 1024 + chan];
        }
    }
    // local pass 1
    float aP = 1.0f, rR = 0.0f, rI = 0.0f;
#pragma unroll
    for (int j = 0; j < 16; ++j) {
        Step s = compute_step<false>(base + (size_t)j * P_, __logf((float)(n0 + j + 1)));
        aP *= s.alpha;
        rR = s.alpha * rR + s.dr;
        rI = s.alpha * rI + s.di;
    }
    __shared__ float lA[256], lR[256], lI[256], pTR[256], pTI[256];
    lA[c * 16 + t] = aP;
    lR[c * 16 + t] = rR;
    lI[c * 16 + t] = rI;
    __syncthreads();
    if (tid < 16) {
        float r = pR, im = pI;
        for (int tt = 0; tt < 16; ++tt) {
            pTR[tid * 16 + tt] = r;
            pTI[tid * 16 + tt] = im;
            float at = lA[tid * 16 + tt];
            r  = at * r  + lR[tid * 16 + tt];
            im = at * im + lI[tid * 16 + tt];
        }
    }
    __syncthreads();
    // pass 2: seeded re-walk + postprocess
    float r = pTR[c * 16 + t], im = pTI[c * 16 + t];
    unsigned short* orow = rho + (size_t)(b * N_ + n0) * DK2_ + k;
#pragma unroll
    for (int j = 0; j < 16; ++j) {
        Step s = compute_step<true>(base + (size_t)j * P_, __logf((float)(n0 + j + 1)));
        r  = s.alpha * r  + s.dr;
        im = s.alpha * im + s.di;
        float readout = r * s.cs + im * s.sn;
        float r2 = r  - s.beta * readout * s.cs;
        float i3 = im - s.beta * readout * s.sn;
        float mod = __fsqrt_rn(r2 * r2 + i3 * i3 + 1e-8f);
        float scl = fmaxf(mod, 1.0f);
        float inv = 1.0f / scl;
        float rr = r2 * inv, ri = i3 * inv;
        float rho_re = rr * s.cs + ri * s.sn;
        float rho_im = -rr * s.sn + ri * s.cs;
        orow[(size_t)j * DK2_]      = f2bf(s.g * rho_re);
        orow[(size_t)j * DK2_ + K_] = f2bf(s.g * rho_im);
    }
}

extern "C" void kernel_launch(void* const* d_in, const int* in_sizes, int n_in,
                              void* d_out, int out_size, void* d_ws, size_t ws_size,
                              hipStream_t stream) {
    const float* x  = (const float*)d_in[0];
    const float* Wp = (const float*)d_in[1];
    const float* bp = (const float*)d_in[2];
    const float* Wr = (const float*)d_in[3];
    const float* rs = (const float*)d_in[4];
    float* out = (float*)d_out;
    char* ws = (char*)d_ws;

    // workspace layout (bytes)
    float* raw = (float*)ws;                                     // 16384*1536*4 = 100,663,296
    unsigned short* xb  = (unsigned short*)(ws + 100663296);     // 33,554,432
    unsigned short* wpb = (unsigned short*)(ws + 134217728);     // 3,145,728
    unsigned short* wrb = (unsigned short*)(ws + 137363456);     // 1,048,576
    float* sA = (float*)(ws + 138412032);                        // 65,536
    float* sR = (float*)(ws + 138477568);                        // 65,536
    float* sI = (float*)(ws + 138543104);                        // 65,536
    unsigned short* rho = xb;  // alias: x_bf16 dead after GEMM1, rho written later

    cvt_kernel<<<16384, 256, 0, stream>>>(x, xb, M_ * D_ / 4);
    cvt_kernel<<<1536, 256, 0, stream>>>(Wp, wpb, P_ * D_ / 4);
    cvt_kernel<<<512, 256, 0, stream>>>(Wr, wrb, D_ * DK2_ / 4);

    gemm_bt<true, false><<<dim3(M_ / 256, P_ / 256), 512, 0, stream>>>(
        xb, wpb, bp, nullptr, raw, M_, P_, D_);

    scan_sum_kernel<<<dim3(16, 16, 4), 256, 0, stream>>>(raw, sA, sR, sI);
    scan_apply_kernel<<<dim3(16, 16, 4), 256, 0, stream>>>(raw, sA, sR, sI, rho);

    gemm_bt<false, true><<<dim3(M_ / 256, D_ / 256), 512, 0, stream>>>(
        rho, wrb, nullptr, rs, out, M_, D_, DK2_);
}

// Round 6
// 154.059 us; speedup vs baseline: 1.6435x; 1.1206x over previous
//
#include <hip/hip_runtime.h>
#include <hip/hip_bf16.h>
#include <cstdint>
#include <cstddef>

#define B_ 4
#define N_ 4096
#define D_ 1024
#define K_ 256
#define M_ (B_ * N_)          // 16384 rows
#define P_ (6 * K_)           // 1536 proj cols
#define DK2_ (2 * K_)         // 512 rho cols

static __device__ __forceinline__ float sigm(float x) {
    return 1.0f / (1.0f + __expf(-x));
}
static __device__ __forceinline__ float softplusf_(float x) {
    return fmaxf(x, 0.0f) + __logf(1.0f + __expf(-fabsf(x)));
}
static __device__ __forceinline__ unsigned short f2bf(float f) {
    uint32_t u = __float_as_uint(f);
    uint32_t r = (u + 0x7FFFu + ((u >> 16) & 1u)) >> 16;
    return (unsigned short)r;
}

#define GATE_BIAS 0.6190392084062235f
#define AMP_MAX 3.0f

typedef __attribute__((ext_vector_type(8))) __bf16 bf16x8;
typedef __attribute__((ext_vector_type(4))) float f32x4;

// async global->LDS, 16B per lane; lds dest must be wave-uniform base (HW adds lane*16)
static __device__ __forceinline__ void gload_lds16(const unsigned short* g, unsigned short* l) {
    __builtin_amdgcn_global_load_lds(
        (const __attribute__((address_space(1))) void*)g,
        (__attribute__((address_space(3))) void*)l, 16, 0, 0);
}

// ---------------- fp32 -> bf16 convert ----------------
__global__ __launch_bounds__(256) void cvt_kernel(const float* __restrict__ src,
                                                  unsigned short* __restrict__ dst, int n4) {
    int i = blockIdx.x * 256 + threadIdx.x;
    if (i < n4) {
        float4 v = reinterpret_cast<const float4*>(src)[i];
        ushort4 o;
        o.x = f2bf(v.x); o.y = f2bf(v.y); o.z = f2bf(v.z); o.w = f2bf(v.w);
        reinterpret_cast<ushort4*>(dst)[i] = o;
    }
}

// ---------------- bf16 GEMM, C[M][N] = A[M][Kd] * B[N][Kd]^T ----------------
// 256 x BN tile (BN=192 or 256), BK=64, 8 waves (2M x 4N), wave tile 128 x BN/4.
// 2 static dbufs, K-loop unrolled x2 with literal buffer names.
// 4 phases/tile, ONE closing barrier per phase. All staging loads for tile t+1
// issue in phase 0 of tile t. Fragment reads are plain C++ loads: the compiler
// emits exact counted lgkmcnt before each consuming MFMA (no manual drain).
// Tile-boundary protocol (race-free): tail of phase 3 = vmcnt(0) ("memory"
// clobber, so no ds_read can cross it) then s_barrier; all waves' staging
// loads have landed before tile t+1's first ds_read. WAR: each phase's
// ds_reads are consumed by MFMAs before its closing barrier; staging always
// targets the other dbuf.

// swizzled fragment read: row r, k-col kc (element units) from [rows]x64 tile
#define FRAG(BUF, r, kc) \
    (*reinterpret_cast<const bf16x8*>(&(BUF)[(size_t)(r) * 64 + (((((kc) >> 3) ^ ((r) & 7)) << 3))]))

template <int BN, bool ADD_BIAS, bool SCALE>
__global__ __launch_bounds__(512, 2) void gemm_bt(const unsigned short* __restrict__ A,
                                                  const unsigned short* __restrict__ Bm,
                                                  const float* __restrict__ bias,
                                                  const float* __restrict__ scale_p,
                                                  float* __restrict__ C, int M, int N, int Kd) {
    constexpr int NB = BN / 64;        // B row-groups == B-frags per wave
    constexpr int WCOL = BN / 4;       // wave column extent
    __shared__ unsigned short As0[256 * 64];
    __shared__ unsigned short Bs0[BN * 64];
    __shared__ unsigned short As1[256 * 64];
    __shared__ unsigned short Bs1[BN * 64];

    const int tid = threadIdx.x;
    const int w = tid >> 6, l = tid & 63;
    const int m0 = blockIdx.x * 256;
    const int n0 = blockIdx.y * BN;
    const int wm = w >> 2, wn = w & 3;         // 2 x 4 wave grid
    const int lr = l & 15, lk = (l >> 4) * 8;
    const int nt = Kd >> 6;                    // 16 (GEMM1) / 8 (GEMM2), always even

    // staging geometry: 512 threads; group G covers rows G*64+srow
    const int srow = tid >> 3;                 // 0..63
    const int sslot = tid & 7;
    const int wbase = tid & ~63;

    f32x4 acc[8][NB];
#pragma unroll
    for (int mi = 0; mi < 8; ++mi)
#pragma unroll
        for (int ni = 0; ni < NB; ++ni) acc[mi][ni] = (f32x4){0.f, 0.f, 0.f, 0.f};

#define STAGE_GROUP(SRC, DST, ROW0G, K0, G)                                           \
    {                                                                                 \
        int row = (G) * 64 + srow;                                                    \
        int col = (K0) + ((sslot ^ (srow & 7)) << 3);                                 \
        gload_lds16((SRC) + (size_t)((ROW0G) + row) * Kd + col,                       \
                    (DST) + (size_t)((((G) * 512 + wbase)) * 8));                     \
    }

#define PHASE(CA, CB, KK, MIH, STAGE_CODE, TAIL_CODE)                                 \
    {                                                                                 \
        _Pragma("unroll") for (int f = 0; f < 4; ++f) {                               \
            int ar = wm * 128 + ((MIH) * 4 + f) * 16 + lr;                            \
            af[f] = FRAG(CA, ar, (KK) + lk);                                          \
        }                                                                             \
        if ((MIH) == 0) {                                                             \
            _Pragma("unroll") for (int f = 0; f < NB; ++f) {                          \
                int br = wn * WCOL + f * 16 + lr;                                     \
                bfr[f] = FRAG(CB, br, (KK) + lk);                                     \
            }                                                                         \
        }                                                                             \
        STAGE_CODE;                                                                   \
        __builtin_amdgcn_s_setprio(1);                                                \
        _Pragma("unroll") for (int mi = 0; mi < 4; ++mi)                              \
            _Pragma("unroll") for (int ni = 0; ni < NB; ++ni)                         \
                acc[(MIH) * 4 + mi][ni] = __builtin_amdgcn_mfma_f32_16x16x32_bf16(    \
                    af[mi], bfr[ni], acc[(MIH) * 4 + mi][ni], 0, 0, 0);               \
        __builtin_amdgcn_s_setprio(0);                                                \
        TAIL_CODE;                                                                    \
        __builtin_amdgcn_s_barrier();                                                 \
    }

#define TILE_STEP(T, CA, CB, PA, PB)                                                  \
    {                                                                                 \
        const int knext = ((T) + 1) * 64;                                             \
        const bool do_stage = ((T) + 1 < nt);                                         \
        bf16x8 af[4], bfr[NB];                                                        \
        PHASE(CA, CB, 0, 0,                                                           \
              if (do_stage) {                                                         \
                  _Pragma("unroll") for (int g = 0; g < 4; ++g)                       \
                      STAGE_GROUP(A, PA, m0, knext, g);                               \
                  _Pragma("unroll") for (int g = 0; g < NB; ++g)                      \
                      STAGE_GROUP(Bm, PB, n0, knext, g);                              \
              },                                                                      \
              {});                                                                    \
        PHASE(CA, CB, 0, 1, {}, {});                                                  \
        PHASE(CA, CB, 32, 0, {}, {});                                                 \
        PHASE(CA, CB, 32, 1, {},                                                      \
              asm volatile("s_waitcnt vmcnt(0)" ::: "memory"));                       \
    }

    // prologue: stage tile 0 into dbuf0, drain, barrier
#pragma unroll
    for (int g = 0; g < 4; ++g) STAGE_GROUP(A, As0, m0, 0, g);
#pragma unroll
    for (int g = 0; g < NB; ++g) STAGE_GROUP(Bm, Bs0, n0, 0, g);
    asm volatile("s_waitcnt vmcnt(0)" ::: "memory");
    __builtin_amdgcn_s_barrier();

    for (int t = 0; t < nt; t += 2) {
        TILE_STEP(t, As0, Bs0, As1, Bs1);
        TILE_STEP(t + 1, As1, Bs1, As0, Bs0);
    }

    float sc = SCALE ? *scale_p : 1.0f;
#pragma unroll
    for (int mi = 0; mi < 8; ++mi) {
        int row = m0 + wm * 128 + mi * 16 + (l >> 4) * 4;
#pragma unroll
        for (int ni = 0; ni < NB; ++ni) {
            int col = n0 + wn * WCOL + ni * 16 + lr;
            float bv = ADD_BIAS ? bias[col] : 0.0f;
#pragma unroll
            for (int j = 0; j < 4; ++j) {
                float v = acc[mi][ni][j] + bv;
                if (SCALE) v *= sc;
                C[(size_t)(row + j) * N + col] = v;
            }
        }
    }
#undef STAGE_GROUP
#undef PHASE
#undef TILE_STEP
}

// ---------------- per-step oscillator math ----------------
struct Step {
    float alpha, dr, di, cs, sn, g, beta;
};
template <bool FULL>
static __device__ __forceinline__ Step compute_step(const float* __restrict__ p, float pos) {
    Step s;
    float a_raw = p[0];
    float o_raw = p[K_];
    float phi   = p[2 * K_];
    float al    = p[3 * K_];
    float A     = AMP_MAX * sigm(a_raw);
    float omega = softplusf_(o_raw);
    float alpha = sigm(al + GATE_BIAS);
    float angle = omega * pos + phi;
    float sn, cs;
    __sincosf(angle, &sn, &cs);
    float oma = 1.0f - alpha;
    s.alpha = alpha;
    s.dr = oma * A * cs;
    s.di = oma * A * sn;
    s.cs = cs;
    s.sn = sn;
    if (FULL) {
        s.g    = sigm(p[4 * K_]);
        s.beta = sigm(p[5 * K_]);
    }
    return s;
}

// ---------------- scan stage 1: chunk + sub-chunk summaries ----------------
// grid: (chunk=16, kgroup=16, b=4); block: 256 = 16 channels x 16 sub-chunks of 16 steps
__global__ __launch_bounds__(256) void scan_sum_kernel(const float* __restrict__ raw,
                                                       float* __restrict__ sA,
                                                       float* __restrict__ sR,
                                                       float* __restrict__ sI,
                                                       float* __restrict__ subA,
                                                       float* __restrict__ subR,
                                                       float* __restrict__ subI) {
    const int tid = threadIdx.x;
    const int c = tid & 15, t = tid >> 4;
    const int chunk = blockIdx.x, kg = blockIdx.y, b = blockIdx.z;
    const int k = kg * 16 + c;
    const int n0 = chunk * 256 + t * 16;
    const float* base = raw + (size_t)(b * N_ + n0) * P_ + k;

    float aP = 1.0f, rR = 0.0f, rI = 0.0f;
#pragma unroll
    for (int j = 0; j < 16; ++j) {
        Step s = compute_step<false>(base + (size_t)j * P_, __logf((float)(n0 + j + 1)));
        aP *= s.alpha;
        rR = s.alpha * rR + s.dr;
        rI = s.alpha * rI + s.di;
    }
    // sub-chunk summary -> global (consumed by scan_apply instead of recompute)
    const int chan = b * K_ + kg * 16 + c;
    const int sidx = (chunk * 16 + t) * 1024 + chan;
    subA[sidx] = aP;
    subR[sidx] = rR;
    subI[sidx] = rI;

    __shared__ float lA[256], lR[256], lI[256];
    lA[c * 16 + t] = aP;
    lR[c * 16 + t] = rR;
    lI[c * 16 + t] = rI;
    __syncthreads();
    if (tid < 16) {
        float a = 1.0f, r = 0.0f, im = 0.0f;
        for (int tt = 0; tt < 16; ++tt) {
            float at = lA[tid * 16 + tt];
            r  = at * r  + lR[tid * 16 + tt];
            im = at * im + lI[tid * 16 + tt];
            a *= at;
        }
        int chanw = b * K_ + kg * 16 + tid;
        sA[chunk * 1024 + chanw] = a;
        sR[chunk * 1024 + chanw] = r;
        sI[chunk * 1024 + chanw] = im;
    }
}

// ---------------- scan stage 2: apply + postprocess -> rho (bf16) ----------------
__global__ __launch_bounds__(256) void scan_apply_kernel(const float* __restrict__ raw,
                                                         const float* __restrict__ sA,
                                                         const float* __restrict__ sR,
                                                         const float* __restrict__ sI,
                                                         const float* __restrict__ subA,
                                                         const float* __restrict__ subR,
                                                         const float* __restrict__ subI,
                                                         unsigned short* __restrict__ rho) {
    const int tid = threadIdx.x;
    const int c = tid & 15, t = tid >> 4;
    const int chunk = blockIdx.x, kg = blockIdx.y, b = blockIdx.z;
    const int k = kg * 16 + c;
    const int n0 = chunk * 256 + t * 16;
    const float* base = raw + (size_t)(b * N_ + n0) * P_ + k;

    // chunk-prefix (exclusive) for channel handled by lanes tid<16
    float pR = 0.0f, pI = 0.0f;
    if (tid < 16) {
        int chan = b * K_ + kg * 16 + tid;
        for (int ch = 0; ch < chunk; ++ch) {
            float a = sA[ch * 1024 + chan];
            pR = a * pR + sR[ch * 1024 + chan];
            pI = a * pI + sI[ch * 1024 + chan];
        }
    }
    // sub-chunk summaries from scan_sum (replaces recompute pass)
    __shared__ float lA[256], lR[256], lI[256], pTR[256], pTI[256];
    {
        const int chan = b * K_ + kg * 16 + c;
        const int sidx = (chunk * 16 + t) * 1024 + chan;
        lA[c * 16 + t] = subA[sidx];
        lR[c * 16 + t] = subR[sidx];
        lI[c * 16 + t] = subI[sidx];
    }
    __syncthreads();
    if (tid < 16) {
        float r = pR, im = pI;
        for (int tt = 0; tt < 16; ++tt) {
            pTR[tid * 16 + tt] = r;
            pTI[tid * 16 + tt] = im;
            float at = lA[tid * 16 + tt];
            r  = at * r  + lR[tid * 16 + tt];
            im = at * im + lI[tid * 16 + tt];
        }
    }
    __syncthreads();
    // seeded walk + postprocess
    float r = pTR[c * 16 + t], im = pTI[c * 16 + t];
    unsigned short* orow = rho + (size_t)(b * N_ + n0) * DK2_ + k;
#pragma unroll
    for (int j = 0; j < 16; ++j) {
        Step s = compute_step<true>(base + (size_t)j * P_, __logf((float)(n0 + j + 1)));
        r  = s.alpha * r  + s.dr;
        im = s.alpha * im + s.di;
        float readout = r * s.cs + im * s.sn;
        float r2 = r  - s.beta * readout * s.cs;
        float i3 = im - s.beta * readout * s.sn;
        float mod = __fsqrt_rn(r2 * r2 + i3 * i3 + 1e-8f);
        float scl = fmaxf(mod, 1.0f);
        float inv = 1.0f / scl;
        float rr = r2 * inv, ri = i3 * inv;
        float rho_re = rr * s.cs + ri * s.sn;
        float rho_im = -rr * s.sn + ri * s.cs;
        orow[(size_t)j * DK2_]      = f2bf(s.g * rho_re);
        orow[(size_t)j * DK2_ + K_] = f2bf(s.g * rho_im);
    }
}

extern "C" void kernel_launch(void* const* d_in, const int* in_sizes, int n_in,
                              void* d_out, int out_size, void* d_ws, size_t ws_size,
                              hipStream_t stream) {
    const float* x  = (const float*)d_in[0];
    const float* Wp = (const float*)d_in[1];
    const float* bp = (const float*)d_in[2];
    const float* Wr = (const float*)d_in[3];
    const float* rs = (const float*)d_in[4];
    float* out = (float*)d_out;
    char* ws = (char*)d_ws;

    // workspace layout (bytes)
    float* raw = (float*)ws;                                     // 16384*1536*4 = 100,663,296
    unsigned short* xb  = (unsigned short*)(ws + 100663296);     // 33,554,432
    unsigned short* wpb = (unsigned short*)(ws + 134217728);     // 3,145,728 (dead after GEMM1)
    unsigned short* wrb = (unsigned short*)(ws + 137363456);     // 1,048,576
    float* sA = (float*)(ws + 138412032);                        // 65,536
    float* sR = (float*)(ws + 138477568);                        // 65,536
    float* sI = (float*)(ws + 138543104);                        // 65,536
    unsigned short* rho = xb;            // alias: x_bf16 dead after GEMM1
    float* subA = (float*)(ws + 134217728);                      // alias wpb: 1 MB
    float* subR = (float*)(ws + 135266304);                      // 1 MB
    float* subI = (float*)(ws + 136314880);                      // 1 MB (ends at wrb)

    cvt_kernel<<<16384, 256, 0, stream>>>(x, xb, M_ * D_ / 4);
    cvt_kernel<<<1536, 256, 0, stream>>>(Wp, wpb, P_ * D_ / 4);
    cvt_kernel<<<512, 256, 0, stream>>>(Wr, wrb, D_ * DK2_ / 4);

    gemm_bt<192, true, false><<<dim3(M_ / 256, P_ / 192), 512, 0, stream>>>(
        xb, wpb, bp, nullptr, raw, M_, P_, D_);

    scan_sum_kernel<<<dim3(16, 16, 4), 256, 0, stream>>>(raw, sA, sR, sI, subA, subR, subI);
    scan_apply_kernel<<<dim3(16, 16, 4), 256, 0, stream>>>(raw, sA, sR, sI, subA, subR, subI, rho);

    gemm_bt<256, false, true><<<dim3(M_ / 256, D_ / 256), 512, 0, stream>>>(
        rho, wrb, nullptr, rs, out, M_, D_, DK2_);
}

// Round 7
// 140.797 us; speedup vs baseline: 1.7984x; 1.0942x over previous
//
#include <hip/hip_runtime.h>
#include <hip/hip_bf16.h>
#include <cstdint>
#include <cstddef>

#define B_ 4
#define N_ 4096
#define D_ 1024
#define K_ 256
#define M_ (B_ * N_)          // 16384 rows
#define P_ (6 * K_)           // 1536 proj cols
#define DK2_ (2 * K_)         // 512 rho cols

static __device__ __forceinline__ float sigm(float x) {
    return 1.0f / (1.0f + __expf(-x));
}
static __device__ __forceinline__ float softplusf_(float x) {
    return fmaxf(x, 0.0f) + __logf(1.0f + __expf(-fabsf(x)));
}
static __device__ __forceinline__ unsigned short f2bf(float f) {
    uint32_t u = __float_as_uint(f);
    uint32_t r = (u + 0x7FFFu + ((u >> 16) & 1u)) >> 16;
    return (unsigned short)r;
}

#define GATE_BIAS 0.6190392084062235f
#define AMP_MAX 3.0f

typedef __attribute__((ext_vector_type(8))) __bf16 bf16x8;
typedef __attribute__((ext_vector_type(4))) float f32x4;

// async global->LDS, 16B per lane; lds dest must be wave-uniform base (HW adds lane*16)
static __device__ __forceinline__ void gload_lds16(const unsigned short* g, unsigned short* l) {
    __builtin_amdgcn_global_load_lds(
        (const __attribute__((address_space(1))) void*)g,
        (__attribute__((address_space(3))) void*)l, 16, 0, 0);
}

// ---------------- fp32 -> bf16 convert ----------------
__global__ __launch_bounds__(256) void cvt_kernel(const float* __restrict__ src,
                                                  unsigned short* __restrict__ dst, int n4) {
    int i = blockIdx.x * 256 + threadIdx.x;
    if (i < n4) {
        float4 v = reinterpret_cast<const float4*>(src)[i];
        ushort4 o;
        o.x = f2bf(v.x); o.y = f2bf(v.y); o.z = f2bf(v.z); o.w = f2bf(v.w);
        reinterpret_cast<ushort4*>(dst)[i] = o;
    }
}

// ---------------- bf16 GEMM, C[M][N] = A[M][Kd] * B[N][Kd]^T ----------------
// 256 x BN tile (BN=192 or 256), BK=64, 8 waves (2M x 4N), wave tile 128 x BN/4.
// 2 static dbufs, K-loop unrolled x2 with literal buffer names.
// 4 phases/tile, ONE closing barrier per phase. All staging loads for tile t+1
// issue in phase 0 of tile t. Fragment reads are plain C++ loads: the compiler
// emits exact counted lgkmcnt before each consuming MFMA (no manual drain).
// Tile-boundary protocol (race-free): tail of phase 3 = vmcnt(0) ("memory"
// clobber, so no ds_read can cross it) then s_barrier. OutT templates the
// epilogue store type (fp16 raw for GEMM1, fp32 out for GEMM2).

// swizzled fragment read: row r, k-col kc (element units) from [rows]x64 tile
#define FRAG(BUF, r, kc) \
    (*reinterpret_cast<const bf16x8*>(&(BUF)[(size_t)(r) * 64 + (((((kc) >> 3) ^ ((r) & 7)) << 3))]))

template <int BN, bool ADD_BIAS, bool SCALE, typename OutT>
__global__ __launch_bounds__(512, 2) void gemm_bt(const unsigned short* __restrict__ A,
                                                  const unsigned short* __restrict__ Bm,
                                                  const float* __restrict__ bias,
                                                  const float* __restrict__ scale_p,
                                                  OutT* __restrict__ C, int M, int N, int Kd) {
    constexpr int NB = BN / 64;        // B-frags per wave
    constexpr int WCOL = BN / 4;       // wave column extent
    __shared__ unsigned short As0[256 * 64];
    __shared__ unsigned short Bs0[BN * 64];
    __shared__ unsigned short As1[256 * 64];
    __shared__ unsigned short Bs1[BN * 64];

    const int tid = threadIdx.x;
    const int w = tid >> 6, l = tid & 63;
    const int m0 = blockIdx.x * 256;
    const int n0 = blockIdx.y * BN;
    const int wm = w >> 2, wn = w & 3;         // 2 x 4 wave grid
    const int lr = l & 15, lk = (l >> 4) * 8;
    const int nt = Kd >> 6;                    // 16 (GEMM1) / 8 (GEMM2), always even

    // staging geometry: 512 threads; group G covers rows G*64+srow
    const int srow = tid >> 3;                 // 0..63
    const int sslot = tid & 7;
    const int wbase = tid & ~63;

    f32x4 acc[8][NB];
#pragma unroll
    for (int mi = 0; mi < 8; ++mi)
#pragma unroll
        for (int ni = 0; ni < NB; ++ni) acc[mi][ni] = (f32x4){0.f, 0.f, 0.f, 0.f};

#define STAGE_GROUP(SRC, DST, ROW0G, K0, G)                                           \
    {                                                                                 \
        int row = (G) * 64 + srow;                                                    \
        int col = (K0) + ((sslot ^ (srow & 7)) << 3);                                 \
        gload_lds16((SRC) + (size_t)((ROW0G) + row) * Kd + col,                       \
                    (DST) + (size_t)((((G) * 512 + wbase)) * 8));                     \
    }

#define PHASE(CA, CB, KK, MIH, STAGE_CODE, TAIL_CODE)                                 \
    {                                                                                 \
        _Pragma("unroll") for (int f = 0; f < 4; ++f) {                               \
            int ar = wm * 128 + ((MIH) * 4 + f) * 16 + lr;                            \
            af[f] = FRAG(CA, ar, (KK) + lk);                                          \
        }                                                                             \
        if ((MIH) == 0) {                                                             \
            _Pragma("unroll") for (int f = 0; f < NB; ++f) {                          \
                int br = wn * WCOL + f * 16 + lr;                                     \
                bfr[f] = FRAG(CB, br, (KK) + lk);                                     \
            }                                                                         \
        }                                                                             \
        STAGE_CODE;                                                                   \
        __builtin_amdgcn_s_setprio(1);                                                \
        _Pragma("unroll") for (int mi = 0; mi < 4; ++mi)                              \
            _Pragma("unroll") for (int ni = 0; ni < NB; ++ni)                         \
                acc[(MIH) * 4 + mi][ni] = __builtin_amdgcn_mfma_f32_16x16x32_bf16(    \
                    af[mi], bfr[ni], acc[(MIH) * 4 + mi][ni], 0, 0, 0);               \
        __builtin_amdgcn_s_setprio(0);                                                \
        TAIL_CODE;                                                                    \
        __builtin_amdgcn_s_barrier();                                                 \
    }

#define TILE_STEP(T, CA, CB, PA, PB)                                                  \
    {                                                                                 \
        const int knext = ((T) + 1) * 64;                                             \
        const bool do_stage = ((T) + 1 < nt);                                         \
        bf16x8 af[4], bfr[NB];                                                        \
        PHASE(CA, CB, 0, 0,                                                           \
              if (do_stage) {                                                         \
                  _Pragma("unroll") for (int g = 0; g < 4; ++g)                       \
                      STAGE_GROUP(A, PA, m0, knext, g);                               \
                  _Pragma("unroll") for (int g = 0; g < NB; ++g)                      \
                      STAGE_GROUP(Bm, PB, n0, knext, g);                              \
              },                                                                      \
              {});                                                                    \
        PHASE(CA, CB, 0, 1, {}, {});                                                  \
        PHASE(CA, CB, 32, 0, {}, {});                                                 \
        PHASE(CA, CB, 32, 1, {},                                                      \
              asm volatile("s_waitcnt vmcnt(0)" ::: "memory"));                       \
    }

    // prologue: stage tile 0 into dbuf0, drain, barrier
#pragma unroll
    for (int g = 0; g < 4; ++g) STAGE_GROUP(A, As0, m0, 0, g);
#pragma unroll
    for (int g = 0; g < NB; ++g) STAGE_GROUP(Bm, Bs0, n0, 0, g);
    asm volatile("s_waitcnt vmcnt(0)" ::: "memory");
    __builtin_amdgcn_s_barrier();

    for (int t = 0; t < nt; t += 2) {
        TILE_STEP(t, As0, Bs0, As1, Bs1);
        TILE_STEP(t + 1, As1, Bs1, As0, Bs0);
    }

    float sc = SCALE ? *scale_p : 1.0f;
#pragma unroll
    for (int mi = 0; mi < 8; ++mi) {
        int row = m0 + wm * 128 + mi * 16 + (l >> 4) * 4;
#pragma unroll
        for (int ni = 0; ni < NB; ++ni) {
            int col = n0 + wn * WCOL + ni * 16 + lr;
            float bv = ADD_BIAS ? bias[col] : 0.0f;
#pragma unroll
            for (int j = 0; j < 4; ++j) {
                float v = acc[mi][ni][j] + bv;
                if (SCALE) v *= sc;
                C[(size_t)(row + j) * N + col] = (OutT)v;
            }
        }
    }
#undef STAGE_GROUP
#undef PHASE
#undef TILE_STEP
}

// ---------------- per-step oscillator math (fp16 raw) ----------------
struct Step {
    float alpha, dr, di, cs, sn, g, beta;
};
template <bool FULL>
static __device__ __forceinline__ Step compute_step(const _Float16* __restrict__ p, float pos) {
    Step s;
    float a_raw = (float)p[0];
    float o_raw = (float)p[K_];
    float phi   = (float)p[2 * K_];
    float al    = (float)p[3 * K_];
    float A     = AMP_MAX * sigm(a_raw);
    float omega = softplusf_(o_raw);
    float alpha = sigm(al + GATE_BIAS);
    float angle = omega * pos + phi;
    float sn, cs;
    __sincosf(angle, &sn, &cs);
    float oma = 1.0f - alpha;
    s.alpha = alpha;
    s.dr = oma * A * cs;
    s.di = oma * A * sn;
    s.cs = cs;
    s.sn = sn;
    if (FULL) {
        s.g    = sigm((float)p[4 * K_]);
        s.beta = sigm((float)p[5 * K_]);
    }
    return s;
}

// ---------------- scan stage 1: chunk + sub-chunk summaries ----------------
// grid: (chunk=16, kgroup=16, b=4); block: 256 = 16 channels x 16 sub-chunks of 16 steps
__global__ __launch_bounds__(256) void scan_sum_kernel(const _Float16* __restrict__ raw,
                                                       float* __restrict__ sA,
                                                       float* __restrict__ sR,
                                                       float* __restrict__ sI,
                                                       float* __restrict__ subA,
                                                       float* __restrict__ subR,
                                                       float* __restrict__ subI) {
    const int tid = threadIdx.x;
    const int c = tid & 15, t = tid >> 4;
    const int chunk = blockIdx.x, kg = blockIdx.y, b = blockIdx.z;
    const int k = kg * 16 + c;
    const int n0 = chunk * 256 + t * 16;
    const _Float16* base = raw + (size_t)(b * N_ + n0) * P_ + k;

    float aP = 1.0f, rR = 0.0f, rI = 0.0f;
#pragma unroll
    for (int j = 0; j < 16; ++j) {
        Step s = compute_step<false>(base + (size_t)j * P_, __logf((float)(n0 + j + 1)));
        aP *= s.alpha;
        rR = s.alpha * rR + s.dr;
        rI = s.alpha * rI + s.di;
    }
    // sub-chunk summary -> global (consumed by scan_apply instead of recompute)
    const int chan = b * K_ + kg * 16 + c;
    const int sidx = (chunk * 16 + t) * 1024 + chan;
    subA[sidx] = aP;
    subR[sidx] = rR;
    subI[sidx] = rI;

    __shared__ float lA[256], lR[256], lI[256];
    lA[c * 16 + t] = aP;
    lR[c * 16 + t] = rR;
    lI[c * 16 + t] = rI;
    __syncthreads();
    if (tid < 16) {
        float a = 1.0f, r = 0.0f, im = 0.0f;
        for (int tt = 0; tt < 16; ++tt) {
            float at = lA[tid * 16 + tt];
            r  = at * r  + lR[tid * 16 + tt];
            im = at * im + lI[tid * 16 + tt];
            a *= at;
        }
        int chanw = b * K_ + kg * 16 + tid;
        sA[chunk * 1024 + chanw] = a;
        sR[chunk * 1024 + chanw] = r;
        sI[chunk * 1024 + chanw] = im;
    }
}

// ---------------- scan stage 2: apply + postprocess -> rho (bf16) ----------------
__global__ __launch_bounds__(256) void scan_apply_kernel(const _Float16* __restrict__ raw,
                                                         const float* __restrict__ sA,
                                                         const float* __restrict__ sR,
                                                         const float* __restrict__ sI,
                                                         const float* __restrict__ subA,
                                                         const float* __restrict__ subR,
                                                         const float* __restrict__ subI,
                                                         unsigned short* __restrict__ rho) {
    const int tid = threadIdx.x;
    const int c = tid & 15, t = tid >> 4;
    const int chunk = blockIdx.x, kg = blockIdx.y, b = blockIdx.z;
    const int k = kg * 16 + c;
    const int n0 = chunk * 256 + t * 16;
    const _Float16* base = raw + (size_t)(b * N_ + n0) * P_ + k;

    // chunk-prefix (exclusive) for channel handled by lanes tid<16
    float pR = 0.0f, pI = 0.0f;
    if (tid < 16) {
        int chan = b * K_ + kg * 16 + tid;
        for (int ch = 0; ch < chunk; ++ch) {
            float a = sA[ch * 1024 + chan];
            pR = a * pR + sR[ch * 1024 + chan];
            pI = a * pI + sI[ch * 1024 + chan];
        }
    }
    // sub-chunk summaries from scan_sum (replaces recompute pass)
    __shared__ float lA[256], lR[256], lI[256], pTR[256], pTI[256];
    {
        const int chan = b * K_ + kg * 16 + c;
        const int sidx = (chunk * 16 + t) * 1024 + chan;
        lA[c * 16 + t] = subA[sidx];
        lR[c * 16 + t] = subR[sidx];
        lI[c * 16 + t] = subI[sidx];
    }
    __syncthreads();
    if (tid < 16) {
        float r = pR, im = pI;
        for (int tt = 0; tt < 16; ++tt) {
            pTR[tid * 16 + tt] = r;
            pTI[tid * 16 + tt] = im;
            float at = lA[tid * 16 + tt];
            r  = at * r  + lR[tid * 16 + tt];
            im = at * im + lI[tid * 16 + tt];
        }
    }
    __syncthreads();
    // seeded walk + postprocess
    float r = pTR[c * 16 + t], im = pTI[c * 16 + t];
    unsigned short* orow = rho + (size_t)(b * N_ + n0) * DK2_ + k;
#pragma unroll
    for (int j = 0; j < 16; ++j) {
        Step s = compute_step<true>(base + (size_t)j * P_, __logf((float)(n0 + j + 1)));
        r  = s.alpha * r  + s.dr;
        im = s.alpha * im + s.di;
        float readout = r * s.cs + im * s.sn;
        float r2 = r  - s.beta * readout * s.cs;
        float i3 = im - s.beta * readout * s.sn;
        float mod = __fsqrt_rn(r2 * r2 + i3 * i3 + 1e-8f);
        float scl = fmaxf(mod, 1.0f);
        float inv = 1.0f / scl;
        float rr = r2 * inv, ri = i3 * inv;
        float rho_re = rr * s.cs + ri * s.sn;
        float rho_im = -rr * s.sn + ri * s.cs;
        orow[(size_t)j * DK2_]      = f2bf(s.g * rho_re);
        orow[(size_t)j * DK2_ + K_] = f2bf(s.g * rho_im);
    }
}

extern "C" void kernel_launch(void* const* d_in, const int* in_sizes, int n_in,
                              void* d_out, int out_size, void* d_ws, size_t ws_size,
                              hipStream_t stream) {
    const float* x  = (const float*)d_in[0];
    const float* Wp = (const float*)d_in[1];
    const float* bp = (const float*)d_in[2];
    const float* Wr = (const float*)d_in[3];
    const float* rs = (const float*)d_in[4];
    float* out = (float*)d_out;
    char* ws = (char*)d_ws;

    // workspace layout (bytes)
    _Float16* raw = (_Float16*)ws;                               // 16384*1536*2 = 50,331,648
    unsigned short* xb  = (unsigned short*)(ws + 100663296);     // 33,554,432
    unsigned short* wpb = (unsigned short*)(ws + 134217728);     // 3,145,728 (dead after GEMM1)
    unsigned short* wrb = (unsigned short*)(ws + 137363456);     // 1,048,576
    float* sA = (float*)(ws + 138412032);                        // 65,536
    float* sR = (float*)(ws + 138477568);                        // 65,536
    float* sI = (float*)(ws + 138543104);                        // 65,536
    unsigned short* rho = xb;            // alias: x_bf16 dead after GEMM1
    float* subA = (float*)(ws + 134217728);                      // alias wpb: 1 MB
    float* subR = (float*)(ws + 135266304);                      // 1 MB
    float* subI = (float*)(ws + 136314880);                      // 1 MB (ends at wrb)

    cvt_kernel<<<16384, 256, 0, stream>>>(x, xb, M_ * D_ / 4);
    cvt_kernel<<<1536, 256, 0, stream>>>(Wp, wpb, P_ * D_ / 4);
    cvt_kernel<<<512, 256, 0, stream>>>(Wr, wrb, D_ * DK2_ / 4);

    gemm_bt<192, true, false, _Float16><<<dim3(M_ / 256, P_ / 192), 512, 0, stream>>>(
        xb, wpb, bp, nullptr, raw, M_, P_, D_);

    scan_sum_kernel<<<dim3(16, 16, 4), 256, 0, stream>>>(raw, sA, sR, sI, subA, subR, subI);
    scan_apply_kernel<<<dim3(16, 16, 4), 256, 0, stream>>>(raw, sA, sR, sI, subA, subR, subI, rho);

    gemm_bt<256, false, true, float><<<dim3(M_ / 256, D_ / 256), 512, 0, stream>>>(
        rho, wrb, nullptr, rs, out, M_, D_, DK2_);
}